// Round 1
// baseline (1568.014 us; speedup 1.0000x reference)
//
#include <hip/hip_runtime.h>
#include <math.h>

constexpr int kB = 16;
constexpr int kN = 1024;
constexpr int kD = 128;
constexpr int kE = 16384;

__device__ __forceinline__ float selu_f(float x) {
    const float scale = 1.0507009873554805f;
    const float alpha = 1.6732632423543772f;
    return x > 0.f ? scale * x : scale * alpha * (expf(x) - 1.f);
}

__device__ __forceinline__ float sigmoid_f(float x) {
    return 1.f / (1.f + expf(-x));
}

// ---------- sort-by-target setup ----------
__global__ void k_count(const int* __restrict__ tgt, int* __restrict__ cnt) {
    int e = blockIdx.x * 256 + threadIdx.x;
    atomicAdd(&cnt[tgt[e]], 1);
}

__global__ void k_scan(const int* __restrict__ cnt, int* __restrict__ cursor) {
    __shared__ int s[kN];
    int t = threadIdx.x;
    int own = cnt[t];
    s[t] = own;
    __syncthreads();
    for (int off = 1; off < kN; off <<= 1) {
        int add = (t >= off) ? s[t - off] : 0;
        __syncthreads();
        s[t] += add;
        __syncthreads();
    }
    cursor[t] = s[t] - own;  // exclusive prefix
}

__global__ void k_scatter(const int* __restrict__ tgt, int* __restrict__ cursor,
                          int* __restrict__ sid) {
    int e = blockIdx.x * 256 + threadIdx.x;
    int tg = tgt[e];
    int pos = atomicAdd(&cursor[tg], 1);
    sid[pos] = e;
}

__global__ void k_gather_ef(const float* __restrict__ edgef, const int* __restrict__ src,
                            const int* __restrict__ tgt, const int* __restrict__ sid,
                            float* __restrict__ efg) {
    int gid = blockIdx.x * 256 + threadIdx.x;  // < kB*kE
    int b = gid >> 14;
    int i = gid & (kE - 1);
    int eid = sid[i];
    efg[gid] = edgef[(size_t)b * kN * kN + (size_t)src[eid] * kN + tgt[eid]];
}

__global__ void k_transpose(const float* __restrict__ Wih, const float* __restrict__ Whh,
                            float* __restrict__ Wtih, float* __restrict__ Wthh) {
    int z = blockIdx.y;
    int idx = blockIdx.x * 256 + threadIdx.x;  // < 384*128
    const float* W = z ? Whh : Wih;
    float* Wt = z ? Wthh : Wtih;
    int j = idx >> 7;    // 0..383
    int k = idx & 127;
    Wt[k * 384 + j] = W[idx];
}

// ---------- message GEMM + selu + fused segment-sum scatter ----------
// grid (kE/64, kB), block 256. Tile: 64 sorted edges x 128 dims, K=256 in 16 chunks + ef/bias tail.
__launch_bounds__(256)
__global__ void k_msg(const float* __restrict__ h, const float* __restrict__ Wmsg,
                      const float* __restrict__ bmsg, const float* __restrict__ efg,
                      const int* __restrict__ src, const int* __restrict__ tgt,
                      const int* __restrict__ sid, float* __restrict__ agg) {
    __shared__ float As[16][64];
    __shared__ float Ws[16 * 128];
    __shared__ int s_src[64], s_tgt[64];
    const int t = threadIdx.x;
    const int b = blockIdx.y;
    const int e_base = blockIdx.x * 64;
    if (t < 64) {
        int eid = sid[e_base + t];
        s_src[t] = src[eid];
        s_tgt[t] = tgt[eid];
    }
    __syncthreads();
    const int eg = t >> 4, dg = t & 15;
    const int e0 = eg * 4, d0 = dg * 8;
    const int se = t >> 2, sq = t & 3;
    const float* hb = h + (size_t)b * (kN * kD);
    float acc[4][8];
#pragma unroll
    for (int e = 0; e < 4; ++e)
#pragma unroll
        for (int i = 0; i < 8; ++i) acc[e][i] = 0.f;

#pragma unroll 1
    for (int kc = 0; kc < 16; ++kc) {
        const int k0 = kc * 16;
        const int row = (k0 < 128) ? s_src[se] : s_tgt[se];
        const int koff = (k0 & 127) + sq * 4;
        const float4 av = *(const float4*)(hb + (size_t)row * kD + koff);
        const float4 w0 = *(const float4*)(Wmsg + k0 * 128 + t * 4);
        const float4 w1 = *(const float4*)(Wmsg + k0 * 128 + 1024 + t * 4);
        __syncthreads();
        As[sq * 4 + 0][se] = av.x;
        As[sq * 4 + 1][se] = av.y;
        As[sq * 4 + 2][se] = av.z;
        As[sq * 4 + 3][se] = av.w;
        *(float4*)&Ws[t * 4] = w0;
        *(float4*)&Ws[1024 + t * 4] = w1;
        __syncthreads();
#pragma unroll
        for (int k = 0; k < 16; ++k) {
            const float4 a = *(const float4*)&As[k][e0];
            const float4 wa = *(const float4*)&Ws[k * 128 + d0];
            const float4 wb = *(const float4*)&Ws[k * 128 + d0 + 4];
            const float aa[4] = {a.x, a.y, a.z, a.w};
            const float ww[8] = {wa.x, wa.y, wa.z, wa.w, wb.x, wb.y, wb.z, wb.w};
#pragma unroll
            for (int e = 0; e < 4; ++e)
#pragma unroll
                for (int i = 0; i < 8; ++i)
                    acc[e][i] = fmaf(aa[e], ww[i], acc[e][i]);
        }
    }
    // tail: ef * W[256] + bias, selu
    float wt[8], bm[8];
#pragma unroll
    for (int i = 0; i < 8; ++i) {
        wt[i] = Wmsg[256 * 128 + d0 + i];
        bm[i] = bmsg[d0 + i];
    }
#pragma unroll
    for (int e = 0; e < 4; ++e) {
        const float efv = efg[b * kE + e_base + e0 + e];
#pragma unroll
        for (int i = 0; i < 8; ++i)
            acc[e][i] = selu_f(fmaf(efv, wt[i], acc[e][i]) + bm[i]);
    }
    // scatter: edges sorted by tgt -> merge runs, then atomicAdd
    int j = 0;
    while (j < 4) {
        const int tg = s_tgt[e0 + j];
        float sum[8];
#pragma unroll
        for (int i = 0; i < 8; ++i) sum[i] = acc[j][i];
        int j2 = j + 1;
        while (j2 < 4 && s_tgt[e0 + j2] == tg) {
#pragma unroll
            for (int i = 0; i < 8; ++i) sum[i] += acc[j2][i];
            ++j2;
        }
        float* dst = agg + ((size_t)b * kN + tg) * kD + d0;
        for (int i = 0; i < 8; ++i) atomicAdd(&dst[i], sum[i]);
        j = j2;
    }
}

// ---------- gi/gh GEMM: C[16384][384] = A[16384][128] @ Wt[128][384] + bias ----------
// grid (16384/64, 3, 2), block 256. z=0: gi from agg; z=1: gh from h.
__launch_bounds__(256)
__global__ void k_gemm(const float* __restrict__ agg, const float* __restrict__ h,
                       const float* __restrict__ Wtih, const float* __restrict__ Wthh,
                       const float* __restrict__ bih, const float* __restrict__ bhh,
                       float* __restrict__ gi, float* __restrict__ gh) {
    __shared__ float As[16][64];
    __shared__ float Ws[16 * 128];
    const int t = threadIdx.x;
    const int r0 = blockIdx.x * 64;
    const int c0 = blockIdx.y * 128;
    const int z = blockIdx.z;
    const float* Asrc = z ? h : agg;
    const float* Wt = z ? Wthh : Wtih;
    const float* bias = z ? bhh : bih;
    float* C = z ? gh : gi;
    const int eg = t >> 4, dg = t & 15;
    const int e0 = eg * 4, d0 = dg * 8;
    const int se = t >> 2, sq = t & 3;
    float acc[4][8];
#pragma unroll
    for (int e = 0; e < 4; ++e)
#pragma unroll
        for (int i = 0; i < 8; ++i) acc[e][i] = 0.f;

#pragma unroll 1
    for (int kc = 0; kc < 8; ++kc) {
        const int k0 = kc * 16;
        const float4 av = *(const float4*)(Asrc + (size_t)(r0 + se) * 128 + k0 + sq * 4);
        const int f1 = t * 4;
        const int k1 = f1 >> 7, c1 = f1 & 127;
        const int f2 = f1 + 1024;
        const int k2 = f2 >> 7, c2 = f2 & 127;
        const float4 w0 = *(const float4*)(Wt + (size_t)(k0 + k1) * 384 + c0 + c1);
        const float4 w1 = *(const float4*)(Wt + (size_t)(k0 + k2) * 384 + c0 + c2);
        __syncthreads();
        As[sq * 4 + 0][se] = av.x;
        As[sq * 4 + 1][se] = av.y;
        As[sq * 4 + 2][se] = av.z;
        As[sq * 4 + 3][se] = av.w;
        *(float4*)&Ws[f1] = w0;
        *(float4*)&Ws[f2] = w1;
        __syncthreads();
#pragma unroll
        for (int k = 0; k < 16; ++k) {
            const float4 a = *(const float4*)&As[k][e0];
            const float4 wa = *(const float4*)&Ws[k * 128 + d0];
            const float4 wb = *(const float4*)&Ws[k * 128 + d0 + 4];
            const float aa[4] = {a.x, a.y, a.z, a.w};
            const float ww[8] = {wa.x, wa.y, wa.z, wa.w, wb.x, wb.y, wb.z, wb.w};
#pragma unroll
            for (int e = 0; e < 4; ++e)
#pragma unroll
                for (int i = 0; i < 8; ++i)
                    acc[e][i] = fmaf(aa[e], ww[i], acc[e][i]);
        }
    }
#pragma unroll
    for (int e = 0; e < 4; ++e) {
        const size_t rbase = (size_t)(r0 + e0 + e) * 384 + c0 + d0;
        float4 o0, o1;
        o0.x = acc[e][0] + bias[c0 + d0 + 0];
        o0.y = acc[e][1] + bias[c0 + d0 + 1];
        o0.z = acc[e][2] + bias[c0 + d0 + 2];
        o0.w = acc[e][3] + bias[c0 + d0 + 3];
        o1.x = acc[e][4] + bias[c0 + d0 + 4];
        o1.y = acc[e][5] + bias[c0 + d0 + 5];
        o1.z = acc[e][6] + bias[c0 + d0 + 6];
        o1.w = acc[e][7] + bias[c0 + d0 + 7];
        *(float4*)&C[rbase] = o0;
        *(float4*)&C[rbase + 4] = o1;
    }
}

// ---------- elementwise GRU ----------
__global__ void k_gru(const float* __restrict__ gi, const float* __restrict__ gh,
                      float* __restrict__ h) {
    const int gid = blockIdx.x * 256 + threadIdx.x;  // < kB*kN*kD
    const int row = gid >> 7, d = gid & 127;
    const size_t base = (size_t)row * 384 + d;
    const float ir = gi[base], iz = gi[base + 128], inn = gi[base + 256];
    const float hr = gh[base], hz = gh[base + 128], hn = gh[base + 256];
    const float hv = h[gid];
    const float r = sigmoid_f(ir + hr);
    const float z = sigmoid_f(iz + hz);
    const float n = tanhf(fmaf(r, hn, inn));
    h[gid] = fmaf(z, hv - n, n);  // (1-z)*n + z*hv
}

// ---------- pooling ----------
__global__ void k_pool(const float* __restrict__ h, float* __restrict__ pooled) {
    const int d = threadIdx.x;      // 128
    const int chunk = blockIdx.x;   // 8
    const int b = blockIdx.y;       // 16
    const float* hp = h + ((size_t)b * kN + chunk * 128) * kD + d;
    float s = 0.f;
    for (int n = 0; n < 128; ++n) s += hp[(size_t)n * kD];
    atomicAdd(&pooled[b * kD + d], s);
}

// ---------- head: selu(p@Wr1+b)@... -> out (16x64) ----------
__global__ void k_head(const float* __restrict__ pooled,
                       const float* __restrict__ Wr1, const float* __restrict__ br1,
                       const float* __restrict__ Wr2, const float* __restrict__ br2,
                       const float* __restrict__ Wpol, const float* __restrict__ bpol,
                       float* __restrict__ out) {
    __shared__ float p[128], t1[128];
    const int b = blockIdx.x, d = threadIdx.x;
    p[d] = pooled[b * 128 + d];
    __syncthreads();
    float acc = br1[d];
    for (int k = 0; k < 128; ++k) acc = fmaf(p[k], Wr1[k * 128 + d], acc);
    t1[d] = selu_f(acc);
    __syncthreads();
    acc = br2[d];
    for (int k = 0; k < 128; ++k) acc = fmaf(t1[k], Wr2[k * 128 + d], acc);
    __syncthreads();
    p[d] = selu_f(acc);
    __syncthreads();
    if (d < 64) {
        float o = bpol[d];
        for (int k = 0; k < 128; ++k) o = fmaf(p[k], Wpol[k * 64 + d], o);
        out[b * 64 + d] = o;
    }
}

extern "C" void kernel_launch(void* const* d_in, const int* in_sizes, int n_in,
                              void* d_out, int out_size, void* d_ws, size_t ws_size,
                              hipStream_t stream) {
    const float* nodef = (const float*)d_in[0];
    const float* edgef = (const float*)d_in[1];
    const int* src = (const int*)d_in[2];
    const int* tgt = (const int*)d_in[3];
    const float* Wmsg = (const float*)d_in[4];
    const float* bmsg = (const float*)d_in[5];
    const float* Wih = (const float*)d_in[6];
    const float* Whh = (const float*)d_in[7];
    const float* bih = (const float*)d_in[8];
    const float* bhh = (const float*)d_in[9];
    const float* Wr1 = (const float*)d_in[10];
    const float* br1 = (const float*)d_in[11];
    const float* Wr2 = (const float*)d_in[12];
    const float* br2 = (const float*)d_in[13];
    const float* Wpol = (const float*)d_in[14];
    const float* bpol = (const float*)d_in[15];
    float* out = (float*)d_out;

    float* ws = (float*)d_ws;
    float* h = ws;                         // 2,097,152
    float* agg = h + 2097152;              // 2,097,152
    float* gi = agg + 2097152;             // 6,291,456
    float* gh = gi + 6291456;              // 6,291,456
    float* efg = gh + 6291456;             // 262,144
    float* Wtih = efg + 262144;            // 49,152
    float* Wthh = Wtih + 49152;            // 49,152
    float* pooled = Wthh + 49152;          // 2,048
    int* cnt = (int*)(pooled + 2048);      // 1,024
    int* cursor = cnt + 1024;              // 1,024
    int* sid = cursor + 1024;              // 16,384

    hipMemcpyAsync(h, nodef, (size_t)2097152 * sizeof(float),
                   hipMemcpyDeviceToDevice, stream);
    hipMemsetAsync(cnt, 0, 1024 * sizeof(int), stream);
    hipMemsetAsync(pooled, 0, 2048 * sizeof(float), stream);

    k_count<<<kE / 256, 256, 0, stream>>>(tgt, cnt);
    k_scan<<<1, 1024, 0, stream>>>(cnt, cursor);
    k_scatter<<<kE / 256, 256, 0, stream>>>(tgt, cursor, sid);
    k_gather_ef<<<(kB * kE) / 256, 256, 0, stream>>>(edgef, src, tgt, sid, efg);
    k_transpose<<<dim3(192, 2), 256, 0, stream>>>(Wih, Whh, Wtih, Wthh);

    for (int it = 0; it < 3; ++it) {
        hipMemsetAsync(agg, 0, (size_t)2097152 * sizeof(float), stream);
        k_msg<<<dim3(kE / 64, kB), 256, 0, stream>>>(h, Wmsg, bmsg, efg, src, tgt, sid, agg);
        k_gemm<<<dim3(256, 3, 2), 256, 0, stream>>>(agg, h, Wtih, Wthh, bih, bhh, gi, gh);
        k_gru<<<(kB * kN * kD) / 256, 256, 0, stream>>>(gi, gh, h);
    }

    k_pool<<<dim3(8, kB), 128, 0, stream>>>(h, pooled);
    k_head<<<kB, 128, 0, stream>>>(pooled, Wr1, br1, Wr2, br2, Wpol, bpol, out);
}

// Round 2
// 495.294 us; speedup vs baseline: 3.1658x; 3.1658x over previous
//
#include <hip/hip_runtime.h>
#include <math.h>

constexpr int kB = 16;
constexpr int kN = 1024;
constexpr int kD = 128;
constexpr int kE = 16384;

__device__ __forceinline__ float selu_f(float x) {
    const float scale = 1.0507009873554805f;
    const float alpha = 1.6732632423543772f;
    return x > 0.f ? scale * x : scale * alpha * (expf(x) - 1.f);
}

__device__ __forceinline__ float sigmoid_f(float x) {
    return 1.f / (1.f + expf(-x));
}

// ---------- sort-by-target setup ----------
__global__ void k_count(const int* __restrict__ tgt, int* __restrict__ cnt) {
    int e = blockIdx.x * 256 + threadIdx.x;
    atomicAdd(&cnt[tgt[e]], 1);
}

// inclusive scan -> cursor (exclusive, mutated by scatter) + rowstart (CSR, preserved)
__global__ void k_scan(const int* __restrict__ cnt, int* __restrict__ cursor,
                       int* __restrict__ rowstart) {
    __shared__ int s[kN];
    int t = threadIdx.x;
    int own = cnt[t];
    s[t] = own;
    __syncthreads();
    for (int off = 1; off < kN; off <<= 1) {
        int add = (t >= off) ? s[t - off] : 0;
        __syncthreads();
        s[t] += add;
        __syncthreads();
    }
    int excl = s[t] - own;
    cursor[t] = excl;
    rowstart[t] = excl;
    if (t == kN - 1) rowstart[kN] = s[t];
}

__global__ void k_scatter(const int* __restrict__ tgt, int* __restrict__ cursor,
                          int* __restrict__ sid) {
    int e = blockIdx.x * 256 + threadIdx.x;
    int tg = tgt[e];
    int pos = atomicAdd(&cursor[tg], 1);
    sid[pos] = e;
}

__global__ void k_ssrc(const int* __restrict__ src, const int* __restrict__ sid,
                       int* __restrict__ ssrc) {
    int i = blockIdx.x * 256 + threadIdx.x;
    ssrc[i] = src[sid[i]];
}

__global__ void k_gather_ef(const float* __restrict__ edgef, const int* __restrict__ src,
                            const int* __restrict__ tgt, const int* __restrict__ sid,
                            float* __restrict__ efg) {
    int gid = blockIdx.x * 256 + threadIdx.x;  // < kB*kE
    int b = gid >> 14;
    int i = gid & (kE - 1);
    int eid = sid[i];
    efg[gid] = edgef[(size_t)b * kN * kN + (size_t)src[eid] * kN + tgt[eid]];
}

// Wcat[k][j] (128 x 640): j<128 -> W1 (src rows of Wmsg), j<256 -> W2 (tgt rows),
// j>=256 -> Whh^T. Wtih[k][j] (128 x 384) = Wih^T. bias640: 0 for j<256, bhh after.
__global__ void k_buildw(const float* __restrict__ Wmsg, const float* __restrict__ Whh,
                         const float* __restrict__ Wih, const float* __restrict__ bhh,
                         float* __restrict__ Wcat, float* __restrict__ Wtih,
                         float* __restrict__ bias640) {
    int k = blockIdx.x;   // 128
    int t = threadIdx.x;  // 256
    for (int j = t; j < 640; j += 256) {
        float v;
        if (j < 128)      v = Wmsg[k * 128 + j];
        else if (j < 256) v = Wmsg[(128 + k) * 128 + (j - 128)];
        else              v = Whh[(size_t)(j - 256) * 128 + k];
        Wcat[k * 640 + j] = v;
    }
    for (int j = t; j < 384; j += 256)
        Wtih[k * 384 + j] = Wih[(size_t)j * 128 + k];
    if (k == 0)
        for (int j = t; j < 640; j += 256)
            bias640[j] = (j < 256) ? 0.f : bhh[j - 256];
}

// ---------- fp32 GEMM: C[M][NC] = A[M][128] @ W[128][NC] + bias ----------
// grid (M/64, NC/128), block 256. Thread tile 4 rows x (4 + 4) cols split 64 apart
// to keep LDS reads at 2-way aliasing (free on gfx950).
template <int NC>
__launch_bounds__(256)
__global__ void k_gemm128(const float* __restrict__ A, const float* __restrict__ W,
                          const float* __restrict__ bias, float* __restrict__ C) {
    __shared__ float As[16][64];
    __shared__ float Ws[16 * 128];
    const int t = threadIdx.x;
    const int r0 = blockIdx.x * 64;
    const int c0 = blockIdx.y * 128;
    const int q = t & 15, eg = t >> 4;
    const int e0 = eg * 4, cl = q * 4;
    const int se = t >> 2, sq = t & 3;
    float acc[4][8];
#pragma unroll
    for (int e = 0; e < 4; ++e)
#pragma unroll
        for (int i = 0; i < 8; ++i) acc[e][i] = 0.f;

#pragma unroll 1
    for (int kc = 0; kc < 8; ++kc) {
        const int k0 = kc * 16;
        const float4 av = *(const float4*)(A + (size_t)(r0 + se) * 128 + k0 + sq * 4);
        const int f1 = t * 4, f2 = f1 + 1024;
        const float4 w0 = *(const float4*)(W + (size_t)(k0 + (f1 >> 7)) * NC + c0 + (f1 & 127));
        const float4 w1 = *(const float4*)(W + (size_t)(k0 + (f2 >> 7)) * NC + c0 + (f2 & 127));
        __syncthreads();
        As[sq * 4 + 0][se] = av.x;
        As[sq * 4 + 1][se] = av.y;
        As[sq * 4 + 2][se] = av.z;
        As[sq * 4 + 3][se] = av.w;
        *(float4*)&Ws[f1] = w0;
        *(float4*)&Ws[f2] = w1;
        __syncthreads();
#pragma unroll
        for (int k = 0; k < 16; ++k) {
            const float4 a = *(const float4*)&As[k][e0];
            const float4 wa = *(const float4*)&Ws[k * 128 + cl];
            const float4 wb = *(const float4*)&Ws[k * 128 + cl + 64];
            const float aa[4] = {a.x, a.y, a.z, a.w};
            const float ww[8] = {wa.x, wa.y, wa.z, wa.w, wb.x, wb.y, wb.z, wb.w};
#pragma unroll
            for (int e = 0; e < 4; ++e)
#pragma unroll
                for (int i = 0; i < 8; ++i)
                    acc[e][i] = fmaf(aa[e], ww[i], acc[e][i]);
        }
    }
    const float4 b0 = *(const float4*)&bias[c0 + cl];
    const float4 b1 = *(const float4*)&bias[c0 + cl + 64];
#pragma unroll
    for (int e = 0; e < 4; ++e) {
        const size_t rbase = (size_t)(r0 + e0 + e) * NC + c0;
        float4 o0, o1;
        o0.x = acc[e][0] + b0.x;
        o0.y = acc[e][1] + b0.y;
        o0.z = acc[e][2] + b0.z;
        o0.w = acc[e][3] + b0.w;
        o1.x = acc[e][4] + b1.x;
        o1.y = acc[e][5] + b1.y;
        o1.z = acc[e][6] + b1.z;
        o1.w = acc[e][7] + b1.w;
        *(float4*)&C[rbase + cl] = o0;
        *(float4*)&C[rbase + cl + 64] = o1;
    }
}

// ---------- per-target edge reduce: agg[b][n][:] = sum selu(HS[src]+HT[n]+ef*w3+b) ----------
// grid (kN, kB), block 128. CSR over sorted edges; no atomics, writes agg once.
__global__ void k_edge(const float* __restrict__ C640, const float* __restrict__ efg,
                       const int* __restrict__ ssrc, const int* __restrict__ rowstart,
                       const float* __restrict__ Wmsg, const float* __restrict__ bmsg,
                       float* __restrict__ agg) {
    const int n = blockIdx.x, b = blockIdx.y, d = threadIdx.x;
    const float w3 = Wmsg[256 * 128 + d];
    const float bm = bmsg[d];
    const float* HSb = C640 + (size_t)b * kN * 640;
    const float htd = HSb[(size_t)n * 640 + 128 + d];
    const float* efb = efg + b * kE;
    const int j0 = rowstart[n], j1 = rowstart[n + 1];
    float accv = 0.f;
    for (int j = j0; j < j1; ++j) {
        const int s = ssrc[j];
        const float ef = efb[j];
        const float v = HSb[(size_t)s * 640 + d] + htd + fmaf(ef, w3, bm);
        accv += selu_f(v);
    }
    agg[((size_t)b * kN + n) * kD + d] = accv;
}

// ---------- elementwise GRU (gh lives in C640 cols 256..639) ----------
__global__ void k_gru(const float* __restrict__ gi, const float* __restrict__ C640,
                      float* __restrict__ h) {
    const int gid = blockIdx.x * 256 + threadIdx.x;  // < kB*kN*kD
    const int row = gid >> 7, d = gid & 127;
    const float* gir = gi + (size_t)row * 384;
    const float* ghr = C640 + (size_t)row * 640 + 256;
    const float ir = gir[d], iz = gir[d + 128], inn = gir[d + 256];
    const float hr = ghr[d], hz = ghr[d + 128], hn = ghr[d + 256];
    const float hv = h[gid];
    const float r = sigmoid_f(ir + hr);
    const float z = sigmoid_f(iz + hz);
    const float n = tanhf(fmaf(r, hn, inn));
    h[gid] = fmaf(z, hv - n, n);
}

// ---------- pooling ----------
__global__ void k_pool(const float* __restrict__ h, float* __restrict__ pooled) {
    const int d = threadIdx.x;
    const int chunk = blockIdx.x;
    const int b = blockIdx.y;
    const float* hp = h + ((size_t)b * kN + chunk * 128) * kD + d;
    float s = 0.f;
    for (int n = 0; n < 128; ++n) s += hp[(size_t)n * kD];
    atomicAdd(&pooled[b * kD + d], s);
}

// ---------- head ----------
__global__ void k_head(const float* __restrict__ pooled,
                       const float* __restrict__ Wr1, const float* __restrict__ br1,
                       const float* __restrict__ Wr2, const float* __restrict__ br2,
                       const float* __restrict__ Wpol, const float* __restrict__ bpol,
                       float* __restrict__ out) {
    __shared__ float p[128], t1[128];
    const int b = blockIdx.x, d = threadIdx.x;
    p[d] = pooled[b * 128 + d];
    __syncthreads();
    float acc = br1[d];
    for (int k = 0; k < 128; ++k) acc = fmaf(p[k], Wr1[k * 128 + d], acc);
    t1[d] = selu_f(acc);
    __syncthreads();
    acc = br2[d];
    for (int k = 0; k < 128; ++k) acc = fmaf(t1[k], Wr2[k * 128 + d], acc);
    __syncthreads();
    p[d] = selu_f(acc);
    __syncthreads();
    if (d < 64) {
        float o = bpol[d];
        for (int k = 0; k < 128; ++k) o = fmaf(p[k], Wpol[k * 64 + d], o);
        out[b * 64 + d] = o;
    }
}

extern "C" void kernel_launch(void* const* d_in, const int* in_sizes, int n_in,
                              void* d_out, int out_size, void* d_ws, size_t ws_size,
                              hipStream_t stream) {
    const float* nodef = (const float*)d_in[0];
    const float* edgef = (const float*)d_in[1];
    const int* src = (const int*)d_in[2];
    const int* tgt = (const int*)d_in[3];
    const float* Wmsg = (const float*)d_in[4];
    const float* bmsg = (const float*)d_in[5];
    const float* Wih = (const float*)d_in[6];
    const float* Whh = (const float*)d_in[7];
    const float* bih = (const float*)d_in[8];
    const float* bhh = (const float*)d_in[9];
    const float* Wr1 = (const float*)d_in[10];
    const float* br1 = (const float*)d_in[11];
    const float* Wr2 = (const float*)d_in[12];
    const float* br2 = (const float*)d_in[13];
    const float* Wpol = (const float*)d_in[14];
    const float* bpol = (const float*)d_in[15];
    float* out = (float*)d_out;

    float* ws = (float*)d_ws;
    float* C640 = ws;                       // 16384*640 = 10,485,760
    float* h = C640 + 10485760;             // 2,097,152
    float* agg = h + 2097152;               // 2,097,152
    float* gi = agg + 2097152;              // 6,291,456
    float* efg = gi + 6291456;              // 262,144
    float* Wcat = efg + 262144;             // 81,920
    float* Wtih = Wcat + 81920;             // 49,152
    float* bias640 = Wtih + 49152;          // 640
    float* pooled = bias640 + 640;          // 2,048
    int* cnt = (int*)(pooled + 2048);       // 1,024
    int* cursor = cnt + 1024;               // 1,024
    int* rowstart = cursor + 1024;          // 1,025
    int* sid = rowstart + 1025;             // 16,384
    int* ssrc = sid + 16384;                // 16,384

    hipMemcpyAsync(h, nodef, (size_t)2097152 * sizeof(float),
                   hipMemcpyDeviceToDevice, stream);
    hipMemsetAsync(cnt, 0, 1024 * sizeof(int), stream);
    hipMemsetAsync(pooled, 0, 2048 * sizeof(float), stream);

    k_count<<<kE / 256, 256, 0, stream>>>(tgt, cnt);
    k_scan<<<1, 1024, 0, stream>>>(cnt, cursor, rowstart);
    k_scatter<<<kE / 256, 256, 0, stream>>>(tgt, cursor, sid);
    k_ssrc<<<kE / 256, 256, 0, stream>>>(src, sid, ssrc);
    k_gather_ef<<<(kB * kE) / 256, 256, 0, stream>>>(edgef, src, tgt, sid, efg);
    k_buildw<<<128, 256, 0, stream>>>(Wmsg, Whh, Wih, bhh, Wcat, Wtih, bias640);

    for (int it = 0; it < 3; ++it) {
        // HS | HT | gh = h @ [W1 | W2 | Whh^T] (+ bias640)
        k_gemm128<640><<<dim3(256, 5), 256, 0, stream>>>(h, Wcat, bias640, C640);
        // per-target selu-reduce, no atomics
        k_edge<<<dim3(kN, kB), 128, 0, stream>>>(C640, efg, ssrc, rowstart, Wmsg, bmsg, agg);
        // gi = agg @ Wih^T + bih
        k_gemm128<384><<<dim3(256, 3), 256, 0, stream>>>(agg, Wtih, bih, gi);
        k_gru<<<(kB * kN * kD) / 256, 256, 0, stream>>>(gi, C640, h);
    }

    k_pool<<<dim3(8, kB), 128, 0, stream>>>(h, pooled);
    k_head<<<kB, 128, 0, stream>>>(pooled, Wr1, br1, Wr2, br2, Wpol, bpol, out);
}

// Round 3
// 368.081 us; speedup vs baseline: 4.2600x; 1.3456x over previous
//
#include <hip/hip_runtime.h>
#include <hip/hip_bf16.h>
#include <math.h>

constexpr int kB = 16;
constexpr int kN = 1024;
constexpr int kD = 128;
constexpr int kE = 16384;

typedef short bf16x8 __attribute__((ext_vector_type(8)));
typedef float f32x4 __attribute__((ext_vector_type(4)));

__device__ __forceinline__ float selu_f(float x) {
    const float scale = 1.0507009873554805f;
    const float alpha = 1.6732632423543772f;
    return x > 0.f ? scale * x : scale * alpha * (expf(x) - 1.f);
}

__device__ __forceinline__ float sigmoid_f(float x) {
    return 1.f / (1.f + expf(-x));
}

// ---------- sort-by-target setup ----------
__global__ void k_count(const int* __restrict__ tgt, int* __restrict__ cnt) {
    int e = blockIdx.x * 256 + threadIdx.x;
    atomicAdd(&cnt[tgt[e]], 1);
}

__global__ void k_scan(const int* __restrict__ cnt, int* __restrict__ cursor,
                       int* __restrict__ rowstart) {
    __shared__ int s[kN];
    int t = threadIdx.x;
    int own = cnt[t];
    s[t] = own;
    __syncthreads();
    for (int off = 1; off < kN; off <<= 1) {
        int add = (t >= off) ? s[t - off] : 0;
        __syncthreads();
        s[t] += add;
        __syncthreads();
    }
    int excl = s[t] - own;
    cursor[t] = excl;
    rowstart[t] = excl;
    if (t == kN - 1) rowstart[kN] = s[t];
}

__global__ void k_scatter(const int* __restrict__ tgt, int* __restrict__ cursor,
                          int* __restrict__ sid) {
    int e = blockIdx.x * 256 + threadIdx.x;
    int tg = tgt[e];
    int pos = atomicAdd(&cursor[tg], 1);
    sid[pos] = e;
}

__global__ void k_ssrc(const int* __restrict__ src, const int* __restrict__ sid,
                       int* __restrict__ ssrc) {
    int i = blockIdx.x * 256 + threadIdx.x;
    ssrc[i] = src[sid[i]];
}

__global__ void k_gather_ef(const float* __restrict__ edgef, const int* __restrict__ src,
                            const int* __restrict__ tgt, const int* __restrict__ sid,
                            float* __restrict__ efg) {
    int gid = blockIdx.x * 256 + threadIdx.x;  // < kB*kE
    int b = gid >> 14;
    int i = gid & (kE - 1);
    int eid = sid[i];
    efg[gid] = edgef[(size_t)b * kN * kN + (size_t)src[eid] * kN + tgt[eid]];
}

// h init: fp32 copy + bf16 shadow
__global__ void k_h0(const float* __restrict__ nodef, float* __restrict__ h,
                     __hip_bfloat16* __restrict__ h_bf) {
    int gid = blockIdx.x * 256 + threadIdx.x;
    float v = nodef[gid];
    h[gid] = v;
    h_bf[gid] = __float2bfloat16(v);
}

// WcatT[j][k] (640 x 128 bf16), j<128: W1^T, j<256: W2^T, j>=256: Whh (raw rows).
// WihB[j][k] (384 x 128 bf16) = Wih raw rows (already B^T for agg @ Wih^T).
// bias640: 0 for j<256, bhh after.
__global__ void k_buildw(const float* __restrict__ Wmsg, const float* __restrict__ Whh,
                         const float* __restrict__ Wih, const float* __restrict__ bhh,
                         __hip_bfloat16* __restrict__ WcatT, __hip_bfloat16* __restrict__ WihB,
                         float* __restrict__ bias640) {
    int j = blockIdx.x;   // 640
    int k = threadIdx.x;  // 128
    float v;
    if (j < 128)      v = Wmsg[k * 128 + j];
    else if (j < 256) v = Wmsg[(128 + k) * 128 + (j - 128)];
    else              v = Whh[(size_t)(j - 256) * 128 + k];
    WcatT[j * 128 + k] = __float2bfloat16(v);
    if (j < 384) WihB[j * 128 + k] = __float2bfloat16(Wih[(size_t)j * 128 + k]);
    if (k == 0) bias640[j] = (j < 256) ? 0.f : bhh[j - 256];
}

// ---------- bf16 MFMA GEMM: C[M][NC] = A[M][128] @ Bt^T[128][NC] + bias ----------
// Block 256 (4 waves), C-tile 128x128, K=128 single-shot. Bt is [NC][128] (k contig).
// LDS layout: 16-B chunks, chunk index = row*16 + (c16 ^ (row&7)) -> 2-way max aliasing
// for both staging writes and frag ds_read_b128 (16 lanes @ 256B row stride).
template <int NC>
__launch_bounds__(256)
__global__ void k_mm(const __hip_bfloat16* __restrict__ A,
                     const __hip_bfloat16* __restrict__ Bt,
                     const float* __restrict__ bias, float* __restrict__ C) {
    __shared__ uint4 As[2048];
    __shared__ uint4 Bs[2048];
    const int t = threadIdx.x;
    const int r0 = blockIdx.x * 128;
    const int c0 = blockIdx.y * 128;
    const uint4* gA = (const uint4*)(A + (size_t)r0 * 128);
    const uint4* gB = (const uint4*)(Bt + (size_t)c0 * 128);
#pragma unroll
    for (int i = 0; i < 8; ++i) {
        const int f = i * 256 + t;
        const int row = f >> 4, c16 = f & 15;
        const int d = row * 16 + (c16 ^ (row & 7));
        As[d] = gA[f];
        Bs[d] = gB[f];
    }
    __syncthreads();
    const int w = t >> 6, l = t & 63;
    const int wm = (w & 1) * 64, wn = (w >> 1) * 64;
    const int lin = l & 15, kq = l >> 4;
    f32x4 acc[4][4] = {};
#pragma unroll
    for (int s = 0; s < 4; ++s) {
        bf16x8 a[4], b[4];
#pragma unroll
        for (int mi = 0; mi < 4; ++mi) {
            const int row = wm + mi * 16 + lin;
            a[mi] = *(const bf16x8*)&As[row * 16 + ((s * 4 + kq) ^ (row & 7))];
        }
#pragma unroll
        for (int ni = 0; ni < 4; ++ni) {
            const int row = wn + ni * 16 + lin;
            b[ni] = *(const bf16x8*)&Bs[row * 16 + ((s * 4 + kq) ^ (row & 7))];
        }
#pragma unroll
        for (int mi = 0; mi < 4; ++mi)
#pragma unroll
            for (int ni = 0; ni < 4; ++ni)
                acc[mi][ni] = __builtin_amdgcn_mfma_f32_16x16x32_bf16(
                    a[mi], b[ni], acc[mi][ni], 0, 0, 0);
    }
    // C/D layout: col = lane&15, row = (lane>>4)*4 + reg
    const int rq = kq * 4;
#pragma unroll
    for (int ni = 0; ni < 4; ++ni) {
        const int col = c0 + wn + ni * 16 + lin;
        const float bv = bias[col];
#pragma unroll
        for (int mi = 0; mi < 4; ++mi) {
            const int row = r0 + wm + mi * 16 + rq;
#pragma unroll
            for (int r = 0; r < 4; ++r)
                C[(size_t)(row + r) * NC + col] = acc[mi][ni][r] + bv;
        }
    }
}

// ---------- per-target edge reduce -> agg (bf16) ----------
__global__ void k_edge(const float* __restrict__ C640, const float* __restrict__ efg,
                       const int* __restrict__ ssrc, const int* __restrict__ rowstart,
                       const float* __restrict__ Wmsg, const float* __restrict__ bmsg,
                       __hip_bfloat16* __restrict__ agg_bf) {
    const int n = blockIdx.x, b = blockIdx.y, d = threadIdx.x;
    const float w3 = Wmsg[256 * 128 + d];
    const float bm = bmsg[d];
    const float* HSb = C640 + (size_t)b * kN * 640;
    const float htd = HSb[(size_t)n * 640 + 128 + d];
    const float* efb = efg + b * kE;
    const int j0 = rowstart[n], j1 = rowstart[n + 1];
    float accv = 0.f;
    for (int j = j0; j < j1; ++j) {
        const int s = ssrc[j];
        const float ef = efb[j];
        const float v = HSb[(size_t)s * 640 + d] + htd + fmaf(ef, w3, bm);
        accv += selu_f(v);
    }
    agg_bf[((size_t)b * kN + n) * kD + d] = __float2bfloat16(accv);
}

// ---------- elementwise GRU (gh in C640 cols 256..639) ----------
__global__ void k_gru(const float* __restrict__ gi, const float* __restrict__ C640,
                      float* __restrict__ h, __hip_bfloat16* __restrict__ h_bf) {
    const int gid = blockIdx.x * 256 + threadIdx.x;
    const int row = gid >> 7, d = gid & 127;
    const float* gir = gi + (size_t)row * 384;
    const float* ghr = C640 + (size_t)row * 640 + 256;
    const float ir = gir[d], iz = gir[d + 128], inn = gir[d + 256];
    const float hr = ghr[d], hz = ghr[d + 128], hn = ghr[d + 256];
    const float hv = h[gid];
    const float r = sigmoid_f(ir + hr);
    const float z = sigmoid_f(iz + hz);
    const float n = tanhf(fmaf(r, hn, inn));
    const float nh = fmaf(z, hv - n, n);
    h[gid] = nh;
    h_bf[gid] = __float2bfloat16(nh);
}

// ---------- pooling ----------
__global__ void k_pool(const float* __restrict__ h, float* __restrict__ pooled) {
    const int d = threadIdx.x;
    const int chunk = blockIdx.x;
    const int b = blockIdx.y;
    const float* hp = h + ((size_t)b * kN + chunk * 128) * kD + d;
    float s = 0.f;
    for (int n = 0; n < 128; ++n) s += hp[(size_t)n * kD];
    atomicAdd(&pooled[b * kD + d], s);
}

// ---------- head ----------
__global__ void k_head(const float* __restrict__ pooled,
                       const float* __restrict__ Wr1, const float* __restrict__ br1,
                       const float* __restrict__ Wr2, const float* __restrict__ br2,
                       const float* __restrict__ Wpol, const float* __restrict__ bpol,
                       float* __restrict__ out) {
    __shared__ float p[128], t1[128];
    const int b = blockIdx.x, d = threadIdx.x;
    p[d] = pooled[b * 128 + d];
    __syncthreads();
    float acc = br1[d];
    for (int k = 0; k < 128; ++k) acc = fmaf(p[k], Wr1[k * 128 + d], acc);
    t1[d] = selu_f(acc);
    __syncthreads();
    acc = br2[d];
    for (int k = 0; k < 128; ++k) acc = fmaf(t1[k], Wr2[k * 128 + d], acc);
    __syncthreads();
    p[d] = selu_f(acc);
    __syncthreads();
    if (d < 64) {
        float o = bpol[d];
        for (int k = 0; k < 128; ++k) o = fmaf(p[k], Wpol[k * 64 + d], o);
        out[b * 64 + d] = o;
    }
}

extern "C" void kernel_launch(void* const* d_in, const int* in_sizes, int n_in,
                              void* d_out, int out_size, void* d_ws, size_t ws_size,
                              hipStream_t stream) {
    const float* nodef = (const float*)d_in[0];
    const float* edgef = (const float*)d_in[1];
    const int* src = (const int*)d_in[2];
    const int* tgt = (const int*)d_in[3];
    const float* Wmsg = (const float*)d_in[4];
    const float* bmsg = (const float*)d_in[5];
    const float* Wih = (const float*)d_in[6];
    const float* Whh = (const float*)d_in[7];
    const float* bih = (const float*)d_in[8];
    const float* bhh = (const float*)d_in[9];
    const float* Wr1 = (const float*)d_in[10];
    const float* br1 = (const float*)d_in[11];
    const float* Wr2 = (const float*)d_in[12];
    const float* br2 = (const float*)d_in[13];
    const float* Wpol = (const float*)d_in[14];
    const float* bpol = (const float*)d_in[15];
    float* out = (float*)d_out;

    float* ws = (float*)d_ws;
    float* C640 = ws;                                   // 10,485,760 f
    float* gi = C640 + 10485760;                        // 6,291,456 f
    float* h = gi + 6291456;                            // 2,097,152 f
    float* efg = h + 2097152;                           // 262,144 f
    float* bias640 = efg + 262144;                      // 1,024 f (640 used)
    float* pooled = bias640 + 1024;                     // 2,048 f
    __hip_bfloat16* h_bf = (__hip_bfloat16*)(pooled + 2048);    // 2,097,152 e (1,048,576 f)
    __hip_bfloat16* agg_bf = h_bf + 2097152;            // 2,097,152 e
    __hip_bfloat16* WcatT = agg_bf + 2097152;           // 81,920 e
    __hip_bfloat16* WihB = WcatT + 81920;               // 49,152 e
    int* cnt = (int*)(WihB + 49152);                    // 1,024
    int* cursor = cnt + 1024;                           // 1,024
    int* rowstart = cursor + 1024;                      // 1,040 (1025 used)
    int* sid = rowstart + 1040;                         // 16,384
    int* ssrc = sid + 16384;                            // 16,384

    hipMemsetAsync(cnt, 0, 1024 * sizeof(int), stream);
    hipMemsetAsync(pooled, 0, 2048 * sizeof(float), stream);

    k_h0<<<(kB * kN * kD) / 256, 256, 0, stream>>>(nodef, h, h_bf);
    k_count<<<kE / 256, 256, 0, stream>>>(tgt, cnt);
    k_scan<<<1, 1024, 0, stream>>>(cnt, cursor, rowstart);
    k_scatter<<<kE / 256, 256, 0, stream>>>(tgt, cursor, sid);
    k_ssrc<<<kE / 256, 256, 0, stream>>>(src, sid, ssrc);
    k_gather_ef<<<(kB * kE) / 256, 256, 0, stream>>>(edgef, src, tgt, sid, efg);
    k_buildw<<<640, 128, 0, stream>>>(Wmsg, Whh, Wih, bhh, WcatT, WihB, bias640);

    for (int it = 0; it < 3; ++it) {
        // HS | HT | gh = h @ [W1 | W2 | Whh^T] + bias640  (bf16 MFMA)
        k_mm<640><<<dim3(128, 5), 256, 0, stream>>>(h_bf, WcatT, bias640, C640);
        // per-target selu-reduce, no atomics, bf16 agg out
        k_edge<<<dim3(kN, kB), 128, 0, stream>>>(C640, efg, ssrc, rowstart, Wmsg, bmsg, agg_bf);
        // gi = agg @ Wih^T + bih  (bf16 MFMA)
        k_mm<384><<<dim3(128, 3), 256, 0, stream>>>(agg_bf, WihB, bih, gi);
        k_gru<<<(kB * kN * kD) / 256, 256, 0, stream>>>(gi, C640, h, h_bf);
    }

    k_pool<<<dim3(8, kB), 128, 0, stream>>>(h, pooled);
    k_head<<<kB, 128, 0, stream>>>(pooled, Wr1, br1, Wr2, br2, Wpol, bpol, out);
}